// Round 10
// baseline (287.338 us; speedup 1.0000x reference)
//
#include <hip/hip_runtime.h>
#include <hip/hip_bf16.h>
#include <math.h>

// Shapes (fixed per reference): B=40, M=8, D=256, H=16x16 -> HW=256, L=15
// Blocks: 8 blocks of 5 samples. Per block: R = 2048 regions, T = 75 tokens.
#define NG 8
#define NB5 5
#define NM 8
#define NHW 256
#define NR 2048
#define ND 256
#define NL 15
#define NT 75
#define NGB 40

// workspace layout (in floats)
#define OFF_S    0                         // s [gb][t][r], aliased later as VTP [gb][m][t][d]
#define SZ_S     (NGB*NT*NR)               // 6,144,000
#define OFF_W    (OFF_S + SZ_S)            // alpha [gb][t][r]
#define OFF_RMAX (OFF_W + SZ_S)            // [gb][seg][r]
#define SZ_RST   (NGB*5*NR)                // 409,600
#define OFF_RSUM (OFF_RMAX + SZ_RST)
#define OFF_SD   (OFF_RSUM + SZ_RST)       // [gb][m][t]
#define SZ_SD    (NGB*NM*NT)
#define OFF_VNS  (OFF_SD + SZ_SD)          // [gb][m][d]; stages NSQ (k1 -> fused k6)
#define SZ_VNS   (NGB*NM*ND)
#define OFF_LG   (OFF_VNS + SZ_VNS)        // logit [gb][t]
#define SZ_LG    (NGB*NT)
#define OFF_LG2  (OFF_LG + SZ_LG)          // logit2 [gb][m][s]
#define SZ_LG2   (NGB*NM*5)
#define OFF_BETA (OFF_LG2 + SZ_LG2)        // [gb][m][t]
#define SZ_BETA  (NGB*NM*NT)
#define OFF_BLK  (OFF_BETA + SZ_BETA)      // [g] (unused since k8/k9 merge)

// Wave-butterfly tail: lane t combines with lane t+s — identical pairings to
// the LDS tree red[t] op= red[t+s], so results are BITWISE identical.
#define SHFL_TAIL_ADD(V)                                                       \
    V += __shfl_down(V, 32); V += __shfl_down(V, 16); V += __shfl_down(V, 8);  \
    V += __shfl_down(V, 4);  V += __shfl_down(V, 2);  V += __shfl_down(V, 1);
#define SHFL_TAIL_MAX(V)                                                       \
    V = fmaxf(V, __shfl_down(V, 32)); V = fmaxf(V, __shfl_down(V, 16));        \
    V = fmaxf(V, __shfl_down(V, 8));  V = fmaxf(V, __shfl_down(V, 4));         \
    V = fmaxf(V, __shfl_down(V, 2));  V = fmaxf(V, __shfl_down(V, 1));

// K1: s[gb][t][m*256+hw] = sum_d v[r][d]*e[t][d].
// Round-5 PROVEN K-loop (closed: r1/r2 spills, r3/r6 latency, r8 conflicts).
// NEW TAIL (after acc stores, zero interaction with the K-loop's registers):
// computes k2's row stats for the two segments fully inside this th's t-range
// (th=0: segs 0,1; th=1: segs 3,4; only seg 2 spans the split). Re-reads the
// just-written Sg rows (this block wrote them; __syncthreads fences global
// block-wide; same L1/L2) and runs k2's loop verbatim -> identical bits.
// Also stages nsq[hw] (k6's first pass) into the VNS slot.
__global__ __launch_bounds__(256, 2) void k1_gemm_s(const float* __restrict__ image,
                                                    const float* __restrict__ text,
                                                    float* __restrict__ ws) {
    __shared__ __align__(16) float A[32][260];   // [dd][hw]
    __shared__ __align__(16) float Et[32][52];   // [dd][w*12 + j]  (wave-padded)
    float* Sg = ws + OFF_S;
    int blk = blockIdx.x;
    int th = blk >= 320 ? 1 : 0;
    int rest = blk - th * 320;
    int m = rest & 7, gb = rest >> 3;
    int g = gb / 5;
    int tb = th * 40;                      // block covers t in [tb, tb+40)
    const float* cell = image + (size_t)(gb * 8 + m) * ND * NHW; // [d][hw]
    int tid = threadIdx.x;
    int lane = tid & 63;
    int w = __builtin_amdgcn_readfirstlane(tid >> 6); // 0..3; wave owns t = tb+w*10+j
    int hw4 = lane * 4;
    int arow = tid >> 6;          // 0..3, A-row base (dd = arow + 4*i)
    int acol = (tid & 63) * 4;    // A col (float4)
    int edd  = tid & 31;          // Et dd
    int etc0 = tid >> 5;          // tcl = etc0 + 8*i
    float4 acc[10];
#pragma unroll
    for (int j = 0; j < 10; ++j) acc[j] = make_float4(0.f, 0.f, 0.f, 0.f);
    float4 nsqa = make_float4(0.f, 0.f, 0.f, 0.f);
    float4 p0, p1, p2, p3, p4, p5, p6, p7;
    float e0, e1, e2, e3, e4;
    const float* tbase = text + (size_t)g * 75 * 256;
#define K1_T(I) ((tb + etc0 + 8 * (I)) > 74 ? 74 : (tb + etc0 + 8 * (I)))
#define K1_LOAD(D0)                                                              \
    p0 = *(const float4*)&cell[(size_t)((D0) + arow +  0) * 256 + acol];         \
    p1 = *(const float4*)&cell[(size_t)((D0) + arow +  4) * 256 + acol];         \
    p2 = *(const float4*)&cell[(size_t)((D0) + arow +  8) * 256 + acol];         \
    p3 = *(const float4*)&cell[(size_t)((D0) + arow + 12) * 256 + acol];         \
    p4 = *(const float4*)&cell[(size_t)((D0) + arow + 16) * 256 + acol];         \
    p5 = *(const float4*)&cell[(size_t)((D0) + arow + 20) * 256 + acol];         \
    p6 = *(const float4*)&cell[(size_t)((D0) + arow + 24) * 256 + acol];         \
    p7 = *(const float4*)&cell[(size_t)((D0) + arow + 28) * 256 + acol];         \
    e0 = tbase[(size_t)K1_T(0) * 256 + (D0) + edd];                              \
    e1 = tbase[(size_t)K1_T(1) * 256 + (D0) + edd];                              \
    e2 = tbase[(size_t)K1_T(2) * 256 + (D0) + edd];                              \
    e3 = tbase[(size_t)K1_T(3) * 256 + (D0) + edd];                              \
    e4 = tbase[(size_t)K1_T(4) * 256 + (D0) + edd];
#define K1_ECOL(I) (((etc0 + 8 * (I)) / 10) * 12 + ((etc0 + 8 * (I)) % 10))
    K1_LOAD(0)
    for (int c = 0; c < 8; ++c) {
        __syncthreads();
        *(float4*)&A[arow +  0][acol] = p0;
        *(float4*)&A[arow +  4][acol] = p1;
        *(float4*)&A[arow +  8][acol] = p2;
        *(float4*)&A[arow + 12][acol] = p3;
        *(float4*)&A[arow + 16][acol] = p4;
        *(float4*)&A[arow + 20][acol] = p5;
        *(float4*)&A[arow + 24][acol] = p6;
        *(float4*)&A[arow + 28][acol] = p7;
        Et[edd][K1_ECOL(0)] = e0;
        Et[edd][K1_ECOL(1)] = e1;
        Et[edd][K1_ECOL(2)] = e2;
        Et[edd][K1_ECOL(3)] = e3;
        Et[edd][K1_ECOL(4)] = e4;
        __syncthreads();
        if (c < 7) { K1_LOAD((c + 1) * 32) }
        for (int dd = 0; dd < 32; ++dd) {
            float4 av = *(const float4*)&A[dd][hw4];
            nsqa.x += av.x * av.x; nsqa.y += av.y * av.y;
            nsqa.z += av.z * av.z; nsqa.w += av.w * av.w;
            float4 q0 = *(const float4*)&Et[dd][w * 12];
            float4 q1 = *(const float4*)&Et[dd][w * 12 + 4];
            float2 q2 = *(const float2*)&Et[dd][w * 12 + 8];
            float ev[10] = {q0.x, q0.y, q0.z, q0.w, q1.x, q1.y, q1.z, q1.w, q2.x, q2.y};
#pragma unroll
            for (int j = 0; j < 10; ++j) {
                acc[j].x += av.x * ev[j]; acc[j].y += av.y * ev[j];
                acc[j].z += av.z * ev[j]; acc[j].w += av.w * ev[j];
            }
        }
    }
#undef K1_LOAD
#undef K1_T
#undef K1_ECOL
#pragma unroll
    for (int j = 0; j < 10; ++j) {
        int t = tb + w * 10 + j;
        if (t < 75)
            *(float4*)&Sg[((size_t)gb * 75 + t) * 2048 + m * 256 + hw4] = acc[j];
    }
    if (th == 0 && w == 0)
        *(float4*)&ws[OFF_VNS + (size_t)(gb * 8 + m) * 256 + hw4] = nsqa;
    // ---- fused k2 partial: segs fully inside this th's range (k2 verbatim) ----
    __syncthreads();   // all Sg stores above visible block-wide
    {
        float* RMAX = ws + OFF_RMAX;
        float* RSUM = ws + OFF_RSUM;
        int r = m * 256 + tid;
        const float* base = Sg + (size_t)gb * 75 * 2048 + r;
        int seg0 = th == 0 ? 0 : 3;
#pragma unroll
        for (int ss = 0; ss < 2; ++ss) {
            int seg = seg0 + ss;
            float v[15]; float mx = -1e30f;
#pragma unroll
            for (int l = 0; l < 15; ++l) {
                v[l] = base[(size_t)(seg * 15 + l) * 2048];
                mx = fmaxf(mx, v[l]);
            }
            float sm = 0.f;
#pragma unroll
            for (int l = 0; l < 15; ++l) sm += __expf(v[l] - mx);
            RMAX[((size_t)gb * 5 + seg) * 2048 + r] = mx;
            RSUM[((size_t)gb * 5 + seg) * 2048 + r] = sm;
        }
    }
}

// K2: row stats for seg 2 ONLY (t 30..44 spans both k1 t-halves; k1's tail
// computed segs 0,1,3,4). Grid 320 = gb x chunk. Same per-r math as always.
__global__ __launch_bounds__(256) void k2_rowstats(float* __restrict__ ws) {
    const float* Sg = ws + OFF_S;
    float* RMAX = ws + OFF_RMAX;
    float* RSUM = ws + OFF_RSUM;
    int blk = blockIdx.x;               // chunk + 8*gb
    int chunk = blk & 7, gb = blk >> 3;
    int r = chunk * 256 + threadIdx.x;
    const float* base = Sg + (size_t)gb * 75 * 2048 + r;
    float v[15]; float mx = -1e30f;
#pragma unroll
    for (int l = 0; l < 15; ++l) {
        v[l] = base[(size_t)(30 + l) * 2048];
        mx = fmaxf(mx, v[l]);
    }
    float sm = 0.f;
#pragma unroll
    for (int l = 0; l < 15; ++l) sm += __expf(v[l] - mx);
    RMAX[((size_t)gb * 5 + 2) * 2048 + r] = mx;
    RSUM[((size_t)gb * 5 + 2) * 2048 + r] = sm;
}

// K3: per (gb,t) column over r=2048. Fast fused reductions (round-4 proven).
__global__ __launch_bounds__(256) void k3_colstats(float* __restrict__ ws) {
    __shared__ float redA[256];
    __shared__ float redB[256];
    __shared__ float red8[8][256];
    __shared__ float bc[2];
    const float* Sg = ws + OFF_S;
    const float* RMAX = ws + OFF_RMAX;
    const float* RSUM = ws + OFF_RSUM;
    float* W = ws + OFF_W;
    float* SD = ws + OFF_SD;
    int blk = blockIdx.x;           // t + 75*gb
    int t = blk % 75, gb = blk / 75;
    int seg = t / 15;
    int tid = threadIdx.x;
    const float* col = Sg + ((size_t)gb * 75 + t) * 2048;
    const float* rmx = RMAX + ((size_t)gb * 5 + seg) * 2048;
    const float* rsm = RSUM + ((size_t)gb * 5 + seg) * 2048;
    float sv[8], ent[8];
    float lmax = -1e30f, lsnt = 0.f;
#pragma unroll
    for (int k = 0; k < 8; ++k) {
        int r = tid + 256 * k;
        float s = col[r];
        sv[k] = s;
        float snt = 4.f * __expf(s - rmx[r]) / rsm[r];
        float e = __expf(snt);
        ent[k] = e;
        lsnt += e;
        lmax = fmaxf(lmax, s);
    }
    // colmax tree
    redA[tid] = lmax; __syncthreads();
    if (tid < 128) redA[tid] = fmaxf(redA[tid], redA[tid + 128]);
    __syncthreads();
    if (tid < 64) {
        float v = fmaxf(redA[tid], redA[tid + 64]);
        SHFL_TAIL_MAX(v)
        if (tid == 0) bc[0] = v;
    }
    __syncthreads();
    float cmax = bc[0];
    float pe[8]; float lse = 0.f;
#pragma unroll
    for (int k = 0; k < 8; ++k) { pe[k] = __expf(sv[k] - cmax); lse += pe[k]; }
    // csum (lse) + csnt (lsnt) trees, fused barrier levels
    redA[tid] = lse; redB[tid] = lsnt; __syncthreads();
    if (tid < 128) { redA[tid] += redA[tid + 128]; redB[tid] += redB[tid + 128]; }
    __syncthreads();
    if (tid < 64) {
        float a = redA[tid] + redA[tid + 64];
        float b = redB[tid] + redB[tid + 64];
        SHFL_TAIL_ADD(a)
        SHFL_TAIL_ADD(b)
        if (tid == 0) { bc[0] = 1.f / b; bc[1] = 1.f / a; }  // inv=1/csnt, icsum=1/csum
    }
    __syncthreads();
    float inv = bc[0], icsum = bc[1];
#pragma unroll
    for (int k = 0; k < 8; ++k)
        W[((size_t)gb * 75 + t) * 2048 + tid + 256 * k] = ent[k] * inv;
#pragma unroll
    for (int k = 0; k < 8; ++k) red8[k][tid] = __expf(pe[k] * icsum);
    __syncthreads();
    if (tid < 128) {
#pragma unroll
        for (int k = 0; k < 8; ++k) red8[k][tid] += red8[k][tid + 128];
    }
    __syncthreads();
    if (tid < 64) {
        float v[8];
#pragma unroll
        for (int k = 0; k < 8; ++k) v[k] = red8[k][tid] + red8[k][tid + 64];
#pragma unroll
        for (int k = 0; k < 8; ++k) { SHFL_TAIL_ADD(v[k]) }
        if (tid == 0) {
#pragma unroll
            for (int k = 0; k < 8; ++k)
                SD[((size_t)gb * 8 + k) * 75 + t] = v[k];
        }
    }
}

// K4: v_tidal partials per m-cell. Round-5 PROVEN: XOR-swizzled V (conflicts
// 4.5M -> 0) + WtT LDS staging (round-6: global W reads regress 58->88us).
__global__ __launch_bounds__(256, 2) void k4_vtidal(const float* __restrict__ image,
                                                    float* __restrict__ ws) {
    __shared__ __align__(16) float V[32 * 256];  // [rr][swizzled d-block]
    __shared__ __align__(16) float WtT[32][52];  // [rr][w*12 + j]
    const float* W = ws + OFF_W;
    float* VTP = ws + OFF_S; // s is dead; reuse
    int blk = blockIdx.x;
    int th = blk >= 320 ? 1 : 0;
    int rest = blk - th * 320;
    int m = rest & 7, gb = rest >> 3;
    int tb = th * 40;
    const float* cell = image + (size_t)(gb * 8 + m) * ND * NHW; // [d][hw]
    int tid = threadIdx.x;
    int lane = tid & 63;
    int w = __builtin_amdgcn_readfirstlane(tid >> 6); // 0..3; wave owns t = tb+w*10+j
    int d4 = lane * 4;
    int rr4  = (tid & 7) * 4;     // V rr base for this thread's float4
    int drow = tid >> 3;          // d = drow + 32*i
    int wrr  = tid & 31;          // WtT rr
    int wtc0 = tid >> 5;          // tcl = wtc0 + 8*i
    float4 acc[10];
#pragma unroll
    for (int j = 0; j < 10; ++j) acc[j] = make_float4(0.f, 0.f, 0.f, 0.f);
    const float* wb = W + (size_t)gb * 75 * 2048 + m * 256;
    float4 p0, p1, p2, p3, p4, p5, p6, p7;
    float w0, w1, w2, w3, w4;
#define K4_T(I) ((tb + wtc0 + 8 * (I)) > 74 ? 74 : (tb + wtc0 + 8 * (I)))
#define K4_LOAD(RC)                                                               \
    p0 = *(const float4*)&cell[(size_t)(drow +   0) * 256 + (RC) * 32 + rr4];     \
    p1 = *(const float4*)&cell[(size_t)(drow +  32) * 256 + (RC) * 32 + rr4];     \
    p2 = *(const float4*)&cell[(size_t)(drow +  64) * 256 + (RC) * 32 + rr4];     \
    p3 = *(const float4*)&cell[(size_t)(drow +  96) * 256 + (RC) * 32 + rr4];     \
    p4 = *(const float4*)&cell[(size_t)(drow + 128) * 256 + (RC) * 32 + rr4];     \
    p5 = *(const float4*)&cell[(size_t)(drow + 160) * 256 + (RC) * 32 + rr4];     \
    p6 = *(const float4*)&cell[(size_t)(drow + 192) * 256 + (RC) * 32 + rr4];     \
    p7 = *(const float4*)&cell[(size_t)(drow + 224) * 256 + (RC) * 32 + rr4];     \
    w0 = wb[(size_t)K4_T(0) * 2048 + (RC) * 32 + wrr];                            \
    w1 = wb[(size_t)K4_T(1) * 2048 + (RC) * 32 + wrr];                            \
    w2 = wb[(size_t)K4_T(2) * 2048 + (RC) * 32 + wrr];                            \
    w3 = wb[(size_t)K4_T(3) * 2048 + (RC) * 32 + wrr];                            \
    w4 = wb[(size_t)K4_T(4) * 2048 + (RC) * 32 + wrr];
#define K4_WCOL(I) (((wtc0 + 8 * (I)) / 10) * 12 + ((wtc0 + 8 * (I)) % 10))
// swizzled V address for (row RR, column D): block (D>>2) ^ ((RR>>2)&7)
#define K4_VADDR(RR, D) (((RR) << 8) + ((((D) >> 2) ^ (((RR) >> 2) & 7)) << 2) + ((D) & 3))
#define K4_VST(P, DOFF)                                                           \
    V[K4_VADDR(rr4 + 0, drow + (DOFF))] = (P).x;                                  \
    V[K4_VADDR(rr4 + 1, drow + (DOFF))] = (P).y;                                  \
    V[K4_VADDR(rr4 + 2, drow + (DOFF))] = (P).z;                                  \
    V[K4_VADDR(rr4 + 3, drow + (DOFF))] = (P).w;
    K4_LOAD(0)
    for (int rc = 0; rc < 8; ++rc) {
        __syncthreads();
        K4_VST(p0,   0) K4_VST(p1,  32) K4_VST(p2,  64) K4_VST(p3,  96)
        K4_VST(p4, 128) K4_VST(p5, 160) K4_VST(p6, 192) K4_VST(p7, 224)
        WtT[wrr][K4_WCOL(0)] = w0;
        WtT[wrr][K4_WCOL(1)] = w1;
        WtT[wrr][K4_WCOL(2)] = w2;
        WtT[wrr][K4_WCOL(3)] = w3;
        WtT[wrr][K4_WCOL(4)] = w4;
        __syncthreads();
        if (rc < 7) { K4_LOAD(rc + 1) }
        for (int rr = 0; rr < 32; ++rr) {
            int sr = (rr >> 2) & 7;
            float4 vv = *(const float4*)&V[(rr << 8) + ((lane ^ sr) << 2)];
            float4 q0 = *(const float4*)&WtT[rr][w * 12];
            float4 q1 = *(const float4*)&WtT[rr][w * 12 + 4];
            float2 q2 = *(const float2*)&WtT[rr][w * 12 + 8];
            float wv[10] = {q0.x, q0.y, q0.z, q0.w, q1.x, q1.y, q1.z, q1.w, q2.x, q2.y};
#pragma unroll
            for (int j = 0; j < 10; ++j) {
                acc[j].x += vv.x * wv[j]; acc[j].y += vv.y * wv[j];
                acc[j].z += vv.z * wv[j]; acc[j].w += vv.w * wv[j];
            }
        }
    }
#undef K4_LOAD
#undef K4_T
#undef K4_WCOL
#undef K4_VADDR
#undef K4_VST
#pragma unroll
    for (int j = 0; j < 10; ++j) {
        int t = tb + w * 10 + j;
        if (t < 75)
            *(float4*)&VTP[((size_t)(gb * 8 + m) * 75 + t) * 256 + d4] = acc[j];
    }
}

// K5+K6 MERGED LAUNCH (round-9 proven): blocks 0..319 = fused k6/k7 path,
// blocks 320..3319 = k5 logit path. Data-independent, disjoint outputs.
__global__ __launch_bounds__(256) void k5k6(const float* __restrict__ image,
                                            const float* __restrict__ text,
                                            float* __restrict__ ws) {
    __shared__ __align__(16) float smem[9672];
    int blk = blockIdx.x;
    int tid = threadIdx.x;
    if (blk < 320) {
        // ---- fused k6+k7 path ----
        float* A     = smem;            // [32][257] = 8224
        float* rn    = smem + 8224;     // 256
        float* ps    = smem + 8480;     // 256
        float* vns_s = smem + 8736;     // 256
        float* rA    = smem + 8992;     // 256
        float* rB    = smem + 9248;     // 256
        float* sdv   = smem + 9504;     // 75 (pad 80)
        float* segs  = smem + 9584;     // 5 (pad 8)
        float* betas = smem + 9592;     // [5][15] flat = 75 (pad 80)
        const float* SD = ws + OFF_SD;
        float* BETA = ws + OFF_BETA;
        float* LG2 = ws + OFF_LG2;
        int m = blk & 7, gb = blk >> 3, g = gb / 5;
        const float* cell = image + (size_t)(gb * 8 + m) * ND * NHW;
        float nsq = ws[OFF_VNS + (size_t)(gb * 8 + m) * 256 + tid];  // staged by k1
        rn[tid] = 1.f / fmaxf(sqrtf(nsq), 1e-12f);
        if (tid < 75) sdv[tid] = SD[((size_t)gb * 8 + m) * 75 + tid];
        int d_loc = tid & 31, sub = tid >> 5; // 8 subs x 32 d
        for (int d0 = 0; d0 < 256; d0 += 32) {
            __syncthreads();
#pragma unroll
            for (int i = 0; i < 32; ++i) A[i * 257 + tid] = cell[(d0 + i) * 256 + tid];
            __syncthreads();
            float partial = 0.f;
#pragma unroll
            for (int k = 0; k < 32; ++k) {
                int hw = sub + 8 * k;
                partial += A[d_loc * 257 + hw] * rn[hw];
            }
            ps[tid] = partial; __syncthreads();
            if (tid < 128) ps[tid] += ps[tid + 128];
            __syncthreads();
            if (tid < 64) ps[tid] += ps[tid + 64];
            __syncthreads();
            if (tid < 32)
                vns_s[d0 + tid] = ps[tid] + ps[tid + 32];
        }
        __syncthreads();
        if (tid < 5) {
            float s = 0.f;
            for (int l = 0; l < 15; ++l) s += sdv[tid * 15 + l];
            segs[tid] = s;
        }
        __syncthreads();
        if (tid < 75) {
            float b = sdv[tid] / segs[tid / 15];
            betas[tid] = b;
            BETA[((size_t)gb * 8 + m) * 75 + tid] = b;
        }
        __syncthreads();
        float vns = vns_s[tid];
        for (int s = 0; s < 5; ++s) {
            float em = 0.f;
#pragma unroll
            for (int l = 0; l < 15; ++l)
                em += betas[s * 15 + l] * text[((size_t)(g * 5 + s) * 15 + l) * 256 + tid];
            rA[tid] = em * em; rB[tid] = em * vns;
            __syncthreads();
            if (tid < 128) { rA[tid] += rA[tid + 128]; rB[tid] += rB[tid + 128]; }
            __syncthreads();
            if (tid < 64) {
                float a = rA[tid] + rA[tid + 64];
                float b = rB[tid] + rB[tid + 64];
                SHFL_TAIL_ADD(a)
                SHFL_TAIL_ADD(b)
                if (tid == 0)
                    LG2[((size_t)gb * 8 + m) * 5 + s] =
                        b / fmaxf(sqrtf(a), 1e-12f) * (1.f / 256.f);
            }
            __syncthreads();  // rA/rB reused next segment
        }
    } else {
        // ---- k5 logit path ----
        float* rA = smem;          // 256
        float* rB = smem + 256;    // 256
        float* rC = smem + 512;    // 256
        const float* VTP = ws + OFF_S;
        float* LG = ws + OFF_LG;
        int b2 = blk - 320;
        int t = b2 % 75, gb = b2 / 75, g = gb / 5;
        float vt = 0.f;
#pragma unroll
        for (int m = 0; m < 8; ++m)
            vt += VTP[((size_t)(gb * 8 + m) * 75 + t) * 256 + tid];
        int seg = t / 15, l = t % 15;
        float ev = text[((size_t)(g * 5 + seg) * 15 + l) * 256 + tid];
        rA[tid] = vt * vt; rB[tid] = ev * ev; rC[tid] = vt * ev;
        __syncthreads();
        if (tid < 128) {
            rA[tid] += rA[tid + 128];
            rB[tid] += rB[tid + 128];
            rC[tid] += rC[tid + 128];
        }
        __syncthreads();
        if (tid < 64) {
            float a = rA[tid] + rA[tid + 64];
            float b = rB[tid] + rB[tid + 64];
            float c = rC[tid] + rC[tid + 64];
            SHFL_TAIL_ADD(a)
            SHFL_TAIL_ADD(b)
            SHFL_TAIL_ADD(c)
            if (tid == 0)
                LG[gb * 75 + t] = c / (fmaxf(sqrtf(a), 1e-12f) * fmaxf(sqrtf(b), 1e-12f));
        }
    }
}

// K8+K9 MERGED: one block computes all 8 g's (identical per-value formulas:
// lsm via tid<200, offsq via strided 2560 loop, regs via tid<40) and tid 0
// sums in the exact g=0..7 order k9 used -> bitwise-identical final scalar.
__global__ __launch_bounds__(256) void k8_final(const float* __restrict__ ws,
                                                float* __restrict__ out) {
    __shared__ float lsm[8][25];
    __shared__ float offsq[8][5][64];
    __shared__ float regs[8][5];
    const float* LG = ws + OFF_LG;
    const float* LG2 = ws + OFF_LG2;
    const float* BETA = ws + OFF_BETA;
    int tid = threadIdx.x;
    if (tid < 200) {
        int g = tid / 25, rem = tid % 25;
        int b = rem / 5, s = rem % 5;
        int gb = g * 5 + b;
        float s1 = 0.f;
        for (int l = 0; l < 15; ++l) s1 += expf(LG[gb * 75 + s * 15 + l]);
        float s2 = 0.f;
        for (int mm = 0; mm < 8; ++mm) s2 += expf(LG2[((size_t)gb * 8 + mm) * 5 + s]);
        float l1 = logf(powf(s1, 0.2f) + 1e-10f);
        float l2 = logf(powf(s2, 0.2f) + 1e-10f);
        lsm[g][rem] = 10.f * (l1 + l2);
    }
    for (int p = tid; p < 2560; p += 256) {
        int g = p / 320, q = p - g * 320;
        int b = q >> 6, mn = q & 63, mm = mn >> 3, nn = mn & 7;
        int gb = g * 5 + b;
        const float* bm = BETA + ((size_t)gb * 8 + mm) * 75;
        const float* bn = BETA + ((size_t)gb * 8 + nn) * 75;
        float acc = 0.f;
        for (int t2 = 0; t2 < 75; ++t2) acc += bm[t2] * bn[t2];
        offsq[g][b][mn] = (mm == nn) ? 0.f : acc * acc;
    }
    __syncthreads();
    if (tid < 40) {
        int g = tid / 5, b = tid % 5;
        float s = 0.f;
        for (int i = 0; i < 64; ++i) s += offsq[g][b][i];
        regs[g][b] = sqrtf(s);
    }
    __syncthreads();
    if (tid == 0) {
        float total = 0.f;
        for (int g = 0; g < 8; ++g) {
            float loss_reg = 0.f;
            for (int b = 0; b < 5; ++b) loss_reg += regs[g][b];
            loss_reg *= 0.2f;
            float pdq = 0.f, pqd = 0.f;
            for (int i = 0; i < 5; ++i) {
                float rsum = 0.f, csum = 0.f;
                for (int j = 0; j < 5; ++j) { rsum += lsm[g][i * 5 + j]; csum += lsm[g][j * 5 + i]; }
                float di = lsm[g][i * 5 + i];
                pdq += -logf(di / rsum + 1e-10f);
                pqd += -logf(di / csum + 1e-10f);
            }
            total += (pdq + pqd) * 0.2f + loss_reg;
        }
        out[0] = total / 9.f;
    }
}

extern "C" void kernel_launch(void* const* d_in, const int* in_sizes, int n_in,
                              void* d_out, int out_size, void* d_ws, size_t ws_size,
                              hipStream_t stream) {
    const float* image = (const float*)d_in[0];
    const float* text  = (const float*)d_in[1];
    float* ws = (float*)d_ws;
    float* out = (float*)d_out;
    hipLaunchKernelGGL(k1_gemm_s,   dim3(640),  dim3(256), 0, stream, image, text, ws);
    hipLaunchKernelGGL(k2_rowstats, dim3(320),  dim3(256), 0, stream, ws);
    hipLaunchKernelGGL(k3_colstats, dim3(3000), dim3(256), 0, stream, ws);
    hipLaunchKernelGGL(k4_vtidal,   dim3(640),  dim3(256), 0, stream, image, ws);
    hipLaunchKernelGGL(k5k6,        dim3(3320), dim3(256), 0, stream, image, text, ws);
    hipLaunchKernelGGL(k8_final,    dim3(1),    dim3(256), 0, stream, ws, out);
}

// Round 11
// 271.460 us; speedup vs baseline: 1.0585x; 1.0585x over previous
//
#include <hip/hip_runtime.h>
#include <hip/hip_bf16.h>
#include <math.h>

// Shapes (fixed per reference): B=40, M=8, D=256, H=16x16 -> HW=256, L=15
// Blocks: 8 blocks of 5 samples. Per block: R = 2048 regions, T = 75 tokens.
#define NG 8
#define NB5 5
#define NM 8
#define NHW 256
#define NR 2048
#define ND 256
#define NL 15
#define NT 75
#define NGB 40

// workspace layout (in floats)
#define OFF_S    0                         // s [gb][t][r], aliased later as VTP [gb][m][t][d]
#define SZ_S     (NGB*NT*NR)               // 6,144,000
#define OFF_W    (OFF_S + SZ_S)            // alpha [gb][t][r]
#define OFF_RMAX (OFF_W + SZ_S)            // [gb][seg][r]
#define SZ_RST   (NGB*5*NR)                // 409,600
#define OFF_RSUM (OFF_RMAX + SZ_RST)
#define OFF_SD   (OFF_RSUM + SZ_RST)       // [gb][m][t]
#define SZ_SD    (NGB*NM*NT)
#define OFF_VNS  (OFF_SD + SZ_SD)          // [gb][m][d]; stages NSQ (k1 -> fused k6)
#define SZ_VNS   (NGB*NM*ND)
#define OFF_LG   (OFF_VNS + SZ_VNS)        // logit [gb][t]
#define SZ_LG    (NGB*NT)
#define OFF_LG2  (OFF_LG + SZ_LG)          // logit2 [gb][m][s]
#define SZ_LG2   (NGB*NM*5)
#define OFF_BETA (OFF_LG2 + SZ_LG2)        // [gb][m][t]
#define SZ_BETA  (NGB*NM*NT)
#define OFF_BLK  (OFF_BETA + SZ_BETA)      // [g]

// Wave-butterfly tail: lane t combines with lane t+s — identical pairings to
// the LDS tree red[t] op= red[t+s], so results are BITWISE identical.
#define SHFL_TAIL_ADD(V)                                                       \
    V += __shfl_down(V, 32); V += __shfl_down(V, 16); V += __shfl_down(V, 8);  \
    V += __shfl_down(V, 4);  V += __shfl_down(V, 2);  V += __shfl_down(V, 1);
#define SHFL_TAIL_MAX(V)                                                       \
    V = fmaxf(V, __shfl_down(V, 32)); V = fmaxf(V, __shfl_down(V, 16));        \
    V = fmaxf(V, __shfl_down(V, 8));  V = fmaxf(V, __shfl_down(V, 4));         \
    V = fmaxf(V, __shfl_down(V, 2));  V = fmaxf(V, __shfl_down(V, 1));

// K1: s[gb][t][m*256+hw] = sum_d v[r][d]*e[t][d].
// Round-5 PROVEN (66-68us). K1 IS CLOSED: five structural attacks lost —
// (r1/r2) min-waves>=3 clamps the allocator and spills the K-loop; (r3/r6)
// global/scalar operand paths latency-serialize; (r8) hw-split's staging was
// a 16-way bank conflict; (r10) fusing k2's row stats into the tail cost more
// than it saved. Also stages nsq[hw] (k6's first pass) into the VNS slot.
__global__ __launch_bounds__(256, 2) void k1_gemm_s(const float* __restrict__ image,
                                                    const float* __restrict__ text,
                                                    float* __restrict__ ws) {
    __shared__ __align__(16) float A[32][260];   // [dd][hw]
    __shared__ __align__(16) float Et[32][52];   // [dd][w*12 + j]  (wave-padded)
    float* Sg = ws + OFF_S;
    int blk = blockIdx.x;
    int th = blk >= 320 ? 1 : 0;
    int rest = blk - th * 320;
    int m = rest & 7, gb = rest >> 3;
    int g = gb / 5;
    int tb = th * 40;                      // block covers t in [tb, tb+40)
    const float* cell = image + (size_t)(gb * 8 + m) * ND * NHW; // [d][hw]
    int tid = threadIdx.x;
    int lane = tid & 63;
    int w = __builtin_amdgcn_readfirstlane(tid >> 6); // 0..3; wave owns t = tb+w*10+j
    int hw4 = lane * 4;
    int arow = tid >> 6;          // 0..3, A-row base (dd = arow + 4*i)
    int acol = (tid & 63) * 4;    // A col (float4)
    int edd  = tid & 31;          // Et dd
    int etc0 = tid >> 5;          // tcl = etc0 + 8*i
    float4 acc[10];
#pragma unroll
    for (int j = 0; j < 10; ++j) acc[j] = make_float4(0.f, 0.f, 0.f, 0.f);
    float4 nsqa = make_float4(0.f, 0.f, 0.f, 0.f);
    float4 p0, p1, p2, p3, p4, p5, p6, p7;
    float e0, e1, e2, e3, e4;
    const float* tbase = text + (size_t)g * 75 * 256;
#define K1_T(I) ((tb + etc0 + 8 * (I)) > 74 ? 74 : (tb + etc0 + 8 * (I)))
#define K1_LOAD(D0)                                                              \
    p0 = *(const float4*)&cell[(size_t)((D0) + arow +  0) * 256 + acol];         \
    p1 = *(const float4*)&cell[(size_t)((D0) + arow +  4) * 256 + acol];         \
    p2 = *(const float4*)&cell[(size_t)((D0) + arow +  8) * 256 + acol];         \
    p3 = *(const float4*)&cell[(size_t)((D0) + arow + 12) * 256 + acol];         \
    p4 = *(const float4*)&cell[(size_t)((D0) + arow + 16) * 256 + acol];         \
    p5 = *(const float4*)&cell[(size_t)((D0) + arow + 20) * 256 + acol];         \
    p6 = *(const float4*)&cell[(size_t)((D0) + arow + 24) * 256 + acol];         \
    p7 = *(const float4*)&cell[(size_t)((D0) + arow + 28) * 256 + acol];         \
    e0 = tbase[(size_t)K1_T(0) * 256 + (D0) + edd];                              \
    e1 = tbase[(size_t)K1_T(1) * 256 + (D0) + edd];                              \
    e2 = tbase[(size_t)K1_T(2) * 256 + (D0) + edd];                              \
    e3 = tbase[(size_t)K1_T(3) * 256 + (D0) + edd];                              \
    e4 = tbase[(size_t)K1_T(4) * 256 + (D0) + edd];
#define K1_ECOL(I) (((etc0 + 8 * (I)) / 10) * 12 + ((etc0 + 8 * (I)) % 10))
    K1_LOAD(0)
    for (int c = 0; c < 8; ++c) {
        __syncthreads();
        *(float4*)&A[arow +  0][acol] = p0;
        *(float4*)&A[arow +  4][acol] = p1;
        *(float4*)&A[arow +  8][acol] = p2;
        *(float4*)&A[arow + 12][acol] = p3;
        *(float4*)&A[arow + 16][acol] = p4;
        *(float4*)&A[arow + 20][acol] = p5;
        *(float4*)&A[arow + 24][acol] = p6;
        *(float4*)&A[arow + 28][acol] = p7;
        Et[edd][K1_ECOL(0)] = e0;
        Et[edd][K1_ECOL(1)] = e1;
        Et[edd][K1_ECOL(2)] = e2;
        Et[edd][K1_ECOL(3)] = e3;
        Et[edd][K1_ECOL(4)] = e4;
        __syncthreads();
        if (c < 7) { K1_LOAD((c + 1) * 32) }
        for (int dd = 0; dd < 32; ++dd) {
            float4 av = *(const float4*)&A[dd][hw4];
            nsqa.x += av.x * av.x; nsqa.y += av.y * av.y;
            nsqa.z += av.z * av.z; nsqa.w += av.w * av.w;
            float4 q0 = *(const float4*)&Et[dd][w * 12];
            float4 q1 = *(const float4*)&Et[dd][w * 12 + 4];
            float2 q2 = *(const float2*)&Et[dd][w * 12 + 8];
            float ev[10] = {q0.x, q0.y, q0.z, q0.w, q1.x, q1.y, q1.z, q1.w, q2.x, q2.y};
#pragma unroll
            for (int j = 0; j < 10; ++j) {
                acc[j].x += av.x * ev[j]; acc[j].y += av.y * ev[j];
                acc[j].z += av.z * ev[j]; acc[j].w += av.w * ev[j];
            }
        }
    }
#undef K1_LOAD
#undef K1_T
#undef K1_ECOL
#pragma unroll
    for (int j = 0; j < 10; ++j) {
        int t = tb + w * 10 + j;
        if (t < 75)
            *(float4*)&Sg[((size_t)gb * 75 + t) * 2048 + m * 256 + hw4] = acc[j];
    }
    if (th == 0 && w == 0)
        *(float4*)&ws[OFF_VNS + (size_t)(gb * 8 + m) * 256 + hw4] = nsqa;
}

// K2: per-(r,seg) max/sumexp. 1600 blocks (gb x seg x chunk), 1 r per thread.
__global__ __launch_bounds__(256) void k2_rowstats(float* __restrict__ ws) {
    const float* Sg = ws + OFF_S;
    float* RMAX = ws + OFF_RMAX;
    float* RSUM = ws + OFF_RSUM;
    int blk = blockIdx.x;               // chunk + 8*(seg + 5*gb)
    int chunk = blk & 7;
    int rest = blk >> 3;
    int seg = rest % 5, gb = rest / 5;
    int r = chunk * 256 + threadIdx.x;
    const float* base = Sg + (size_t)gb * 75 * 2048 + r;
    float v[15]; float mx = -1e30f;
#pragma unroll
    for (int l = 0; l < 15; ++l) {
        v[l] = base[(size_t)(seg * 15 + l) * 2048];
        mx = fmaxf(mx, v[l]);
    }
    float sm = 0.f;
#pragma unroll
    for (int l = 0; l < 15; ++l) sm += __expf(v[l] - mx);
    RMAX[((size_t)gb * 5 + seg) * 2048 + r] = mx;
    RSUM[((size_t)gb * 5 + seg) * 2048 + r] = sm;
}

// K3: per (gb,t) column over r=2048. Fast fused reductions (round-4 proven).
__global__ __launch_bounds__(256) void k3_colstats(float* __restrict__ ws) {
    __shared__ float redA[256];
    __shared__ float redB[256];
    __shared__ float red8[8][256];
    __shared__ float bc[2];
    const float* Sg = ws + OFF_S;
    const float* RMAX = ws + OFF_RMAX;
    const float* RSUM = ws + OFF_RSUM;
    float* W = ws + OFF_W;
    float* SD = ws + OFF_SD;
    int blk = blockIdx.x;           // t + 75*gb
    int t = blk % 75, gb = blk / 75;
    int seg = t / 15;
    int tid = threadIdx.x;
    const float* col = Sg + ((size_t)gb * 75 + t) * 2048;
    const float* rmx = RMAX + ((size_t)gb * 5 + seg) * 2048;
    const float* rsm = RSUM + ((size_t)gb * 5 + seg) * 2048;
    float sv[8], ent[8];
    float lmax = -1e30f, lsnt = 0.f;
#pragma unroll
    for (int k = 0; k < 8; ++k) {
        int r = tid + 256 * k;
        float s = col[r];
        sv[k] = s;
        float snt = 4.f * __expf(s - rmx[r]) / rsm[r];
        float e = __expf(snt);
        ent[k] = e;
        lsnt += e;
        lmax = fmaxf(lmax, s);
    }
    // colmax tree
    redA[tid] = lmax; __syncthreads();
    if (tid < 128) redA[tid] = fmaxf(redA[tid], redA[tid + 128]);
    __syncthreads();
    if (tid < 64) {
        float v = fmaxf(redA[tid], redA[tid + 64]);
        SHFL_TAIL_MAX(v)
        if (tid == 0) bc[0] = v;
    }
    __syncthreads();
    float cmax = bc[0];
    float pe[8]; float lse = 0.f;
#pragma unroll
    for (int k = 0; k < 8; ++k) { pe[k] = __expf(sv[k] - cmax); lse += pe[k]; }
    // csum (lse) + csnt (lsnt) trees, fused barrier levels
    redA[tid] = lse; redB[tid] = lsnt; __syncthreads();
    if (tid < 128) { redA[tid] += redA[tid + 128]; redB[tid] += redB[tid + 128]; }
    __syncthreads();
    if (tid < 64) {
        float a = redA[tid] + redA[tid + 64];
        float b = redB[tid] + redB[tid + 64];
        SHFL_TAIL_ADD(a)
        SHFL_TAIL_ADD(b)
        if (tid == 0) { bc[0] = 1.f / b; bc[1] = 1.f / a; }  // inv=1/csnt, icsum=1/csum
    }
    __syncthreads();
    float inv = bc[0], icsum = bc[1];
#pragma unroll
    for (int k = 0; k < 8; ++k)
        W[((size_t)gb * 75 + t) * 2048 + tid + 256 * k] = ent[k] * inv;
#pragma unroll
    for (int k = 0; k < 8; ++k) red8[k][tid] = __expf(pe[k] * icsum);
    __syncthreads();
    if (tid < 128) {
#pragma unroll
        for (int k = 0; k < 8; ++k) red8[k][tid] += red8[k][tid + 128];
    }
    __syncthreads();
    if (tid < 64) {
        float v[8];
#pragma unroll
        for (int k = 0; k < 8; ++k) v[k] = red8[k][tid] + red8[k][tid + 64];
#pragma unroll
        for (int k = 0; k < 8; ++k) { SHFL_TAIL_ADD(v[k]) }
        if (tid == 0) {
#pragma unroll
            for (int k = 0; k < 8; ++k)
                SD[((size_t)gb * 8 + k) * 75 + t] = v[k];
        }
    }
}

// K4: v_tidal partials per m-cell. Round-5 PROVEN: XOR-swizzled V (conflicts
// 4.5M -> 0) + WtT LDS staging (round-6: global W reads regress 58->88us).
__global__ __launch_bounds__(256, 2) void k4_vtidal(const float* __restrict__ image,
                                                    float* __restrict__ ws) {
    __shared__ __align__(16) float V[32 * 256];  // [rr][swizzled d-block]
    __shared__ __align__(16) float WtT[32][52];  // [rr][w*12 + j]
    const float* W = ws + OFF_W;
    float* VTP = ws + OFF_S; // s is dead; reuse
    int blk = blockIdx.x;
    int th = blk >= 320 ? 1 : 0;
    int rest = blk - th * 320;
    int m = rest & 7, gb = rest >> 3;
    int tb = th * 40;
    const float* cell = image + (size_t)(gb * 8 + m) * ND * NHW; // [d][hw]
    int tid = threadIdx.x;
    int lane = tid & 63;
    int w = __builtin_amdgcn_readfirstlane(tid >> 6); // 0..3; wave owns t = tb+w*10+j
    int d4 = lane * 4;
    int rr4  = (tid & 7) * 4;     // V rr base for this thread's float4
    int drow = tid >> 3;          // d = drow + 32*i
    int wrr  = tid & 31;          // WtT rr
    int wtc0 = tid >> 5;          // tcl = wtc0 + 8*i
    float4 acc[10];
#pragma unroll
    for (int j = 0; j < 10; ++j) acc[j] = make_float4(0.f, 0.f, 0.f, 0.f);
    const float* wb = W + (size_t)gb * 75 * 2048 + m * 256;
    float4 p0, p1, p2, p3, p4, p5, p6, p7;
    float w0, w1, w2, w3, w4;
#define K4_T(I) ((tb + wtc0 + 8 * (I)) > 74 ? 74 : (tb + wtc0 + 8 * (I)))
#define K4_LOAD(RC)                                                               \
    p0 = *(const float4*)&cell[(size_t)(drow +   0) * 256 + (RC) * 32 + rr4];     \
    p1 = *(const float4*)&cell[(size_t)(drow +  32) * 256 + (RC) * 32 + rr4];     \
    p2 = *(const float4*)&cell[(size_t)(drow +  64) * 256 + (RC) * 32 + rr4];     \
    p3 = *(const float4*)&cell[(size_t)(drow +  96) * 256 + (RC) * 32 + rr4];     \
    p4 = *(const float4*)&cell[(size_t)(drow + 128) * 256 + (RC) * 32 + rr4];     \
    p5 = *(const float4*)&cell[(size_t)(drow + 160) * 256 + (RC) * 32 + rr4];     \
    p6 = *(const float4*)&cell[(size_t)(drow + 192) * 256 + (RC) * 32 + rr4];     \
    p7 = *(const float4*)&cell[(size_t)(drow + 224) * 256 + (RC) * 32 + rr4];     \
    w0 = wb[(size_t)K4_T(0) * 2048 + (RC) * 32 + wrr];                            \
    w1 = wb[(size_t)K4_T(1) * 2048 + (RC) * 32 + wrr];                            \
    w2 = wb[(size_t)K4_T(2) * 2048 + (RC) * 32 + wrr];                            \
    w3 = wb[(size_t)K4_T(3) * 2048 + (RC) * 32 + wrr];                            \
    w4 = wb[(size_t)K4_T(4) * 2048 + (RC) * 32 + wrr];
#define K4_WCOL(I) (((wtc0 + 8 * (I)) / 10) * 12 + ((wtc0 + 8 * (I)) % 10))
// swizzled V address for (row RR, column D): block (D>>2) ^ ((RR>>2)&7)
#define K4_VADDR(RR, D) (((RR) << 8) + ((((D) >> 2) ^ (((RR) >> 2) & 7)) << 2) + ((D) & 3))
#define K4_VST(P, DOFF)                                                           \
    V[K4_VADDR(rr4 + 0, drow + (DOFF))] = (P).x;                                  \
    V[K4_VADDR(rr4 + 1, drow + (DOFF))] = (P).y;                                  \
    V[K4_VADDR(rr4 + 2, drow + (DOFF))] = (P).z;                                  \
    V[K4_VADDR(rr4 + 3, drow + (DOFF))] = (P).w;
    K4_LOAD(0)
    for (int rc = 0; rc < 8; ++rc) {
        __syncthreads();
        K4_VST(p0,   0) K4_VST(p1,  32) K4_VST(p2,  64) K4_VST(p3,  96)
        K4_VST(p4, 128) K4_VST(p5, 160) K4_VST(p6, 192) K4_VST(p7, 224)
        WtT[wrr][K4_WCOL(0)] = w0;
        WtT[wrr][K4_WCOL(1)] = w1;
        WtT[wrr][K4_WCOL(2)] = w2;
        WtT[wrr][K4_WCOL(3)] = w3;
        WtT[wrr][K4_WCOL(4)] = w4;
        __syncthreads();
        if (rc < 7) { K4_LOAD(rc + 1) }
        for (int rr = 0; rr < 32; ++rr) {
            int sr = (rr >> 2) & 7;
            float4 vv = *(const float4*)&V[(rr << 8) + ((lane ^ sr) << 2)];
            float4 q0 = *(const float4*)&WtT[rr][w * 12];
            float4 q1 = *(const float4*)&WtT[rr][w * 12 + 4];
            float2 q2 = *(const float2*)&WtT[rr][w * 12 + 8];
            float wv[10] = {q0.x, q0.y, q0.z, q0.w, q1.x, q1.y, q1.z, q1.w, q2.x, q2.y};
#pragma unroll
            for (int j = 0; j < 10; ++j) {
                acc[j].x += vv.x * wv[j]; acc[j].y += vv.y * wv[j];
                acc[j].z += vv.z * wv[j]; acc[j].w += vv.w * wv[j];
            }
        }
    }
#undef K4_LOAD
#undef K4_T
#undef K4_WCOL
#undef K4_VADDR
#undef K4_VST
#pragma unroll
    for (int j = 0; j < 10; ++j) {
        int t = tb + w * 10 + j;
        if (t < 75)
            *(float4*)&VTP[((size_t)(gb * 8 + m) * 75 + t) * 256 + d4] = acc[j];
    }
}

// K5+K6 MERGED LAUNCH (round-9 proven): blocks 0..319 = fused k6/k7 path,
// blocks 320..3319 = k5 logit path. Data-independent, disjoint outputs.
__global__ __launch_bounds__(256) void k5k6(const float* __restrict__ image,
                                            const float* __restrict__ text,
                                            float* __restrict__ ws) {
    __shared__ __align__(16) float smem[9672];
    int blk = blockIdx.x;
    int tid = threadIdx.x;
    if (blk < 320) {
        // ---- fused k6+k7 path ----
        float* A     = smem;            // [32][257] = 8224
        float* rn    = smem + 8224;     // 256
        float* ps    = smem + 8480;     // 256
        float* vns_s = smem + 8736;     // 256
        float* rA    = smem + 8992;     // 256
        float* rB    = smem + 9248;     // 256
        float* sdv   = smem + 9504;     // 75 (pad 80)
        float* segs  = smem + 9584;     // 5 (pad 8)
        float* betas = smem + 9592;     // [5][15] flat = 75 (pad 80)
        const float* SD = ws + OFF_SD;
        float* BETA = ws + OFF_BETA;
        float* LG2 = ws + OFF_LG2;
        int m = blk & 7, gb = blk >> 3, g = gb / 5;
        const float* cell = image + (size_t)(gb * 8 + m) * ND * NHW;
        float nsq = ws[OFF_VNS + (size_t)(gb * 8 + m) * 256 + tid];  // staged by k1
        rn[tid] = 1.f / fmaxf(sqrtf(nsq), 1e-12f);
        if (tid < 75) sdv[tid] = SD[((size_t)gb * 8 + m) * 75 + tid];
        int d_loc = tid & 31, sub = tid >> 5; // 8 subs x 32 d
        for (int d0 = 0; d0 < 256; d0 += 32) {
            __syncthreads();
#pragma unroll
            for (int i = 0; i < 32; ++i) A[i * 257 + tid] = cell[(d0 + i) * 256 + tid];
            __syncthreads();
            float partial = 0.f;
#pragma unroll
            for (int k = 0; k < 32; ++k) {
                int hw = sub + 8 * k;
                partial += A[d_loc * 257 + hw] * rn[hw];
            }
            ps[tid] = partial; __syncthreads();
            if (tid < 128) ps[tid] += ps[tid + 128];
            __syncthreads();
            if (tid < 64) ps[tid] += ps[tid + 64];
            __syncthreads();
            if (tid < 32)
                vns_s[d0 + tid] = ps[tid] + ps[tid + 32];
        }
        __syncthreads();
        if (tid < 5) {
            float s = 0.f;
            for (int l = 0; l < 15; ++l) s += sdv[tid * 15 + l];
            segs[tid] = s;
        }
        __syncthreads();
        if (tid < 75) {
            float b = sdv[tid] / segs[tid / 15];
            betas[tid] = b;
            BETA[((size_t)gb * 8 + m) * 75 + tid] = b;
        }
        __syncthreads();
        float vns = vns_s[tid];
        for (int s = 0; s < 5; ++s) {
            float em = 0.f;
#pragma unroll
            for (int l = 0; l < 15; ++l)
                em += betas[s * 15 + l] * text[((size_t)(g * 5 + s) * 15 + l) * 256 + tid];
            rA[tid] = em * em; rB[tid] = em * vns;
            __syncthreads();
            if (tid < 128) { rA[tid] += rA[tid + 128]; rB[tid] += rB[tid + 128]; }
            __syncthreads();
            if (tid < 64) {
                float a = rA[tid] + rA[tid + 64];
                float b = rB[tid] + rB[tid + 64];
                SHFL_TAIL_ADD(a)
                SHFL_TAIL_ADD(b)
                if (tid == 0)
                    LG2[((size_t)gb * 8 + m) * 5 + s] =
                        b / fmaxf(sqrtf(a), 1e-12f) * (1.f / 256.f);
            }
            __syncthreads();  // rA/rB reused next segment
        }
    } else {
        // ---- k5 logit path ----
        float* rA = smem;          // 256
        float* rB = smem + 256;    // 256
        float* rC = smem + 512;    // 256
        const float* VTP = ws + OFF_S;
        float* LG = ws + OFF_LG;
        int b2 = blk - 320;
        int t = b2 % 75, gb = b2 / 75, g = gb / 5;
        float vt = 0.f;
#pragma unroll
        for (int m = 0; m < 8; ++m)
            vt += VTP[((size_t)(gb * 8 + m) * 75 + t) * 256 + tid];
        int seg = t / 15, l = t % 15;
        float ev = text[((size_t)(g * 5 + seg) * 15 + l) * 256 + tid];
        rA[tid] = vt * vt; rB[tid] = ev * ev; rC[tid] = vt * ev;
        __syncthreads();
        if (tid < 128) {
            rA[tid] += rA[tid + 128];
            rB[tid] += rB[tid + 128];
            rC[tid] += rC[tid + 128];
        }
        __syncthreads();
        if (tid < 64) {
            float a = rA[tid] + rA[tid + 64];
            float b = rB[tid] + rB[tid + 64];
            float c = rC[tid] + rC[tid + 64];
            SHFL_TAIL_ADD(a)
            SHFL_TAIL_ADD(b)
            SHFL_TAIL_ADD(c)
            if (tid == 0)
                LG[gb * 75 + t] = c / (fmaxf(sqrtf(a), 1e-12f) * fmaxf(sqrtf(b), 1e-12f));
        }
    }
}

// K8: per-g block assembly -> BLK[g]  (8 blocks — round-10 showed the
// single-block merge serializes the offsq work onto one CU, ~15us loss)
__global__ __launch_bounds__(256) void k8_final(float* __restrict__ ws) {
    __shared__ float lsm[5][5];
    __shared__ float offsq[5][64];
    __shared__ float regs[5];
    const float* LG = ws + OFF_LG;
    const float* LG2 = ws + OFF_LG2;
    const float* BETA = ws + OFF_BETA;
    float* BLK = ws + OFF_BLK;
    int g = blockIdx.x;
    int tid = threadIdx.x;
    if (tid < 25) {
        int b = tid / 5, s = tid % 5;
        int gb = g * 5 + b;
        float s1 = 0.f;
        for (int l = 0; l < 15; ++l) s1 += expf(LG[gb * 75 + s * 15 + l]);
        float s2 = 0.f;
        for (int mm = 0; mm < 8; ++mm) s2 += expf(LG2[((size_t)gb * 8 + mm) * 5 + s]);
        float l1 = logf(powf(s1, 0.2f) + 1e-10f);
        float l2 = logf(powf(s2, 0.2f) + 1e-10f);
        lsm[b][s] = 10.f * (l1 + l2);
    }
    for (int p = tid; p < 320; p += 256) {
        int b = p >> 6, mn = p & 63, mm = mn >> 3, nn = mn & 7;
        int gb = g * 5 + b;
        const float* bm = BETA + ((size_t)gb * 8 + mm) * 75;
        const float* bn = BETA + ((size_t)gb * 8 + nn) * 75;
        float acc = 0.f;
        for (int t2 = 0; t2 < 75; ++t2) acc += bm[t2] * bn[t2];
        offsq[b][mn] = (mm == nn) ? 0.f : acc * acc;
    }
    __syncthreads();
    if (tid < 5) {
        float s = 0.f;
        for (int i = 0; i < 64; ++i) s += offsq[tid][i];
        regs[tid] = sqrtf(s);
    }
    __syncthreads();
    if (tid == 0) {
        float loss_reg = 0.f;
        for (int b = 0; b < 5; ++b) loss_reg += regs[b];
        loss_reg *= 0.2f;
        float pdq = 0.f, pqd = 0.f;
        for (int i = 0; i < 5; ++i) {
            float rsum = 0.f, csum = 0.f;
            for (int j = 0; j < 5; ++j) { rsum += lsm[i][j]; csum += lsm[j][i]; }
            float di = lsm[i][i];
            pdq += -logf(di / rsum + 1e-10f);
            pqd += -logf(di / csum + 1e-10f);
        }
        BLK[g] = (pdq + pqd) * 0.2f + loss_reg;
    }
}

__global__ void k9_out(const float* __restrict__ ws, float* __restrict__ out) {
    if (threadIdx.x == 0) {
        float s = 0.f;
        for (int g2 = 0; g2 < 8; ++g2) s += ws[OFF_BLK + g2];
        out[0] = s / 9.f;
    }
}

extern "C" void kernel_launch(void* const* d_in, const int* in_sizes, int n_in,
                              void* d_out, int out_size, void* d_ws, size_t ws_size,
                              hipStream_t stream) {
    const float* image = (const float*)d_in[0];
    const float* text  = (const float*)d_in[1];
    float* ws = (float*)d_ws;
    float* out = (float*)d_out;
    hipLaunchKernelGGL(k1_gemm_s,   dim3(640),  dim3(256), 0, stream, image, text, ws);
    hipLaunchKernelGGL(k2_rowstats, dim3(1600), dim3(256), 0, stream, ws);
    hipLaunchKernelGGL(k3_colstats, dim3(3000), dim3(256), 0, stream, ws);
    hipLaunchKernelGGL(k4_vtidal,   dim3(640),  dim3(256), 0, stream, image, ws);
    hipLaunchKernelGGL(k5k6,        dim3(3320), dim3(256), 0, stream, image, text, ws);
    hipLaunchKernelGGL(k8_final,    dim3(8),    dim3(256), 0, stream, ws);
    hipLaunchKernelGGL(k9_out,      dim3(1),    dim3(64),  0, stream, ws, out);
}

// Round 12
// 251.245 us; speedup vs baseline: 1.1437x; 1.0805x over previous
//
#include <hip/hip_runtime.h>
#include <hip/hip_bf16.h>
#include <math.h>

// Shapes (fixed per reference): B=40, M=8, D=256, H=16x16 -> HW=256, L=15
// Blocks: 8 blocks of 5 samples. Per block: R = 2048 regions, T = 75 tokens.
#define NG 8
#define NB5 5
#define NM 8
#define NHW 256
#define NR 2048
#define ND 256
#define NL 15
#define NT 75
#define NGB 40

// workspace layout (in floats)
#define OFF_S    0                         // s [gb][t][r], aliased later as VTP [gb][m][t][d]
#define SZ_S     (NGB*NT*NR)               // 6,144,000
#define OFF_W    (OFF_S + SZ_S)            // alpha [gb][t][r]
#define OFF_RMAX (OFF_W + SZ_S)            // [gb][seg][r]
#define SZ_RST   (NGB*5*NR)                // 409,600
#define OFF_RSUM (OFF_RMAX + SZ_RST)
#define OFF_SD   (OFF_RSUM + SZ_RST)       // [gb][m][t]
#define SZ_SD    (NGB*NM*NT)
#define OFF_VNS  (OFF_SD + SZ_SD)          // [gb][m][d]; k1 stages NSQ, k4 writes VNS
#define SZ_VNS   (NGB*NM*ND)
#define OFF_LG   (OFF_VNS + SZ_VNS)        // logit [gb][t]
#define SZ_LG    (NGB*NT)
#define OFF_LG2  (OFF_LG + SZ_LG)          // logit2 [gb][m][s]
#define SZ_LG2   (NGB*NM*5)
#define OFF_BETA (OFF_LG2 + SZ_LG2)        // [gb][m][t]
#define SZ_BETA  (NGB*NM*NT)
#define OFF_BLK  (OFF_BETA + SZ_BETA)      // [g]

// Wave-butterfly tail: lane t combines with lane t+s — identical pairings to
// the LDS tree red[t] op= red[t+s], so results are BITWISE identical.
#define SHFL_TAIL_ADD(V)                                                       \
    V += __shfl_down(V, 32); V += __shfl_down(V, 16); V += __shfl_down(V, 8);  \
    V += __shfl_down(V, 4);  V += __shfl_down(V, 2);  V += __shfl_down(V, 1);
#define SHFL_TAIL_MAX(V)                                                       \
    V = fmaxf(V, __shfl_down(V, 32)); V = fmaxf(V, __shfl_down(V, 16));        \
    V = fmaxf(V, __shfl_down(V, 8));  V = fmaxf(V, __shfl_down(V, 4));         \
    V = fmaxf(V, __shfl_down(V, 2));  V = fmaxf(V, __shfl_down(V, 1));

// K1: s[gb][t][m*256+hw] = sum_d v[r][d]*e[t][d].
// Round-5 PROVEN (66-68us). K1 IS CLOSED: five structural attacks lost —
// (r1/r2) min-waves>=3 clamps the allocator and spills the K-loop; (r3/r6)
// global/scalar operand paths latency-serialize; (r8) hw-split's staging was
// a 16-way bank conflict; (r10) fusing k2's row stats into the tail cost more
// than it saved. Also stages nsq[hw] (for rn) into the VNS slot.
__global__ __launch_bounds__(256, 2) void k1_gemm_s(const float* __restrict__ image,
                                                    const float* __restrict__ text,
                                                    float* __restrict__ ws) {
    __shared__ __align__(16) float A[32][260];   // [dd][hw]
    __shared__ __align__(16) float Et[32][52];   // [dd][w*12 + j]  (wave-padded)
    float* Sg = ws + OFF_S;
    int blk = blockIdx.x;
    int th = blk >= 320 ? 1 : 0;
    int rest = blk - th * 320;
    int m = rest & 7, gb = rest >> 3;
    int g = gb / 5;
    int tb = th * 40;                      // block covers t in [tb, tb+40)
    const float* cell = image + (size_t)(gb * 8 + m) * ND * NHW; // [d][hw]
    int tid = threadIdx.x;
    int lane = tid & 63;
    int w = __builtin_amdgcn_readfirstlane(tid >> 6); // 0..3; wave owns t = tb+w*10+j
    int hw4 = lane * 4;
    int arow = tid >> 6;          // 0..3, A-row base (dd = arow + 4*i)
    int acol = (tid & 63) * 4;    // A col (float4)
    int edd  = tid & 31;          // Et dd
    int etc0 = tid >> 5;          // tcl = etc0 + 8*i
    float4 acc[10];
#pragma unroll
    for (int j = 0; j < 10; ++j) acc[j] = make_float4(0.f, 0.f, 0.f, 0.f);
    float4 nsqa = make_float4(0.f, 0.f, 0.f, 0.f);
    float4 p0, p1, p2, p3, p4, p5, p6, p7;
    float e0, e1, e2, e3, e4;
    const float* tbase = text + (size_t)g * 75 * 256;
#define K1_T(I) ((tb + etc0 + 8 * (I)) > 74 ? 74 : (tb + etc0 + 8 * (I)))
#define K1_LOAD(D0)                                                              \
    p0 = *(const float4*)&cell[(size_t)((D0) + arow +  0) * 256 + acol];         \
    p1 = *(const float4*)&cell[(size_t)((D0) + arow +  4) * 256 + acol];         \
    p2 = *(const float4*)&cell[(size_t)((D0) + arow +  8) * 256 + acol];         \
    p3 = *(const float4*)&cell[(size_t)((D0) + arow + 12) * 256 + acol];         \
    p4 = *(const float4*)&cell[(size_t)((D0) + arow + 16) * 256 + acol];         \
    p5 = *(const float4*)&cell[(size_t)((D0) + arow + 20) * 256 + acol];         \
    p6 = *(const float4*)&cell[(size_t)((D0) + arow + 24) * 256 + acol];         \
    p7 = *(const float4*)&cell[(size_t)((D0) + arow + 28) * 256 + acol];         \
    e0 = tbase[(size_t)K1_T(0) * 256 + (D0) + edd];                              \
    e1 = tbase[(size_t)K1_T(1) * 256 + (D0) + edd];                              \
    e2 = tbase[(size_t)K1_T(2) * 256 + (D0) + edd];                              \
    e3 = tbase[(size_t)K1_T(3) * 256 + (D0) + edd];                              \
    e4 = tbase[(size_t)K1_T(4) * 256 + (D0) + edd];
#define K1_ECOL(I) (((etc0 + 8 * (I)) / 10) * 12 + ((etc0 + 8 * (I)) % 10))
    K1_LOAD(0)
    for (int c = 0; c < 8; ++c) {
        __syncthreads();
        *(float4*)&A[arow +  0][acol] = p0;
        *(float4*)&A[arow +  4][acol] = p1;
        *(float4*)&A[arow +  8][acol] = p2;
        *(float4*)&A[arow + 12][acol] = p3;
        *(float4*)&A[arow + 16][acol] = p4;
        *(float4*)&A[arow + 20][acol] = p5;
        *(float4*)&A[arow + 24][acol] = p6;
        *(float4*)&A[arow + 28][acol] = p7;
        Et[edd][K1_ECOL(0)] = e0;
        Et[edd][K1_ECOL(1)] = e1;
        Et[edd][K1_ECOL(2)] = e2;
        Et[edd][K1_ECOL(3)] = e3;
        Et[edd][K1_ECOL(4)] = e4;
        __syncthreads();
        if (c < 7) { K1_LOAD((c + 1) * 32) }
        for (int dd = 0; dd < 32; ++dd) {
            float4 av = *(const float4*)&A[dd][hw4];
            nsqa.x += av.x * av.x; nsqa.y += av.y * av.y;
            nsqa.z += av.z * av.z; nsqa.w += av.w * av.w;
            float4 q0 = *(const float4*)&Et[dd][w * 12];
            float4 q1 = *(const float4*)&Et[dd][w * 12 + 4];
            float2 q2 = *(const float2*)&Et[dd][w * 12 + 8];
            float ev[10] = {q0.x, q0.y, q0.z, q0.w, q1.x, q1.y, q1.z, q1.w, q2.x, q2.y};
#pragma unroll
            for (int j = 0; j < 10; ++j) {
                acc[j].x += av.x * ev[j]; acc[j].y += av.y * ev[j];
                acc[j].z += av.z * ev[j]; acc[j].w += av.w * ev[j];
            }
        }
    }
#undef K1_LOAD
#undef K1_T
#undef K1_ECOL
#pragma unroll
    for (int j = 0; j < 10; ++j) {
        int t = tb + w * 10 + j;
        if (t < 75)
            *(float4*)&Sg[((size_t)gb * 75 + t) * 2048 + m * 256 + hw4] = acc[j];
    }
    if (th == 0 && w == 0)
        *(float4*)&ws[OFF_VNS + (size_t)(gb * 8 + m) * 256 + hw4] = nsqa;
}

// K2: per-(r,seg) max/sumexp. 1600 blocks (gb x seg x chunk), 1 r per thread.
__global__ __launch_bounds__(256) void k2_rowstats(float* __restrict__ ws) {
    const float* Sg = ws + OFF_S;
    float* RMAX = ws + OFF_RMAX;
    float* RSUM = ws + OFF_RSUM;
    int blk = blockIdx.x;               // chunk + 8*(seg + 5*gb)
    int chunk = blk & 7;
    int rest = blk >> 3;
    int seg = rest % 5, gb = rest / 5;
    int r = chunk * 256 + threadIdx.x;
    const float* base = Sg + (size_t)gb * 75 * 2048 + r;
    float v[15]; float mx = -1e30f;
#pragma unroll
    for (int l = 0; l < 15; ++l) {
        v[l] = base[(size_t)(seg * 15 + l) * 2048];
        mx = fmaxf(mx, v[l]);
    }
    float sm = 0.f;
#pragma unroll
    for (int l = 0; l < 15; ++l) sm += __expf(v[l] - mx);
    RMAX[((size_t)gb * 5 + seg) * 2048 + r] = mx;
    RSUM[((size_t)gb * 5 + seg) * 2048 + r] = sm;
}

// K3: per (gb,t) column over r=2048. Fast fused reductions (round-4 proven).
__global__ __launch_bounds__(256) void k3_colstats(float* __restrict__ ws) {
    __shared__ float redA[256];
    __shared__ float redB[256];
    __shared__ float red8[8][256];
    __shared__ float bc[2];
    const float* Sg = ws + OFF_S;
    const float* RMAX = ws + OFF_RMAX;
    const float* RSUM = ws + OFF_RSUM;
    float* W = ws + OFF_W;
    float* SD = ws + OFF_SD;
    int blk = blockIdx.x;           // t + 75*gb
    int t = blk % 75, gb = blk / 75;
    int seg = t / 15;
    int tid = threadIdx.x;
    const float* col = Sg + ((size_t)gb * 75 + t) * 2048;
    const float* rmx = RMAX + ((size_t)gb * 5 + seg) * 2048;
    const float* rsm = RSUM + ((size_t)gb * 5 + seg) * 2048;
    float sv[8], ent[8];
    float lmax = -1e30f, lsnt = 0.f;
#pragma unroll
    for (int k = 0; k < 8; ++k) {
        int r = tid + 256 * k;
        float s = col[r];
        sv[k] = s;
        float snt = 4.f * __expf(s - rmx[r]) / rsm[r];
        float e = __expf(snt);
        ent[k] = e;
        lsnt += e;
        lmax = fmaxf(lmax, s);
    }
    // colmax tree
    redA[tid] = lmax; __syncthreads();
    if (tid < 128) redA[tid] = fmaxf(redA[tid], redA[tid + 128]);
    __syncthreads();
    if (tid < 64) {
        float v = fmaxf(redA[tid], redA[tid + 64]);
        SHFL_TAIL_MAX(v)
        if (tid == 0) bc[0] = v;
    }
    __syncthreads();
    float cmax = bc[0];
    float pe[8]; float lse = 0.f;
#pragma unroll
    for (int k = 0; k < 8; ++k) { pe[k] = __expf(sv[k] - cmax); lse += pe[k]; }
    // csum (lse) + csnt (lsnt) trees, fused barrier levels
    redA[tid] = lse; redB[tid] = lsnt; __syncthreads();
    if (tid < 128) { redA[tid] += redA[tid + 128]; redB[tid] += redB[tid + 128]; }
    __syncthreads();
    if (tid < 64) {
        float a = redA[tid] + redA[tid + 64];
        float b = redB[tid] + redB[tid + 64];
        SHFL_TAIL_ADD(a)
        SHFL_TAIL_ADD(b)
        if (tid == 0) { bc[0] = 1.f / b; bc[1] = 1.f / a; }  // inv=1/csnt, icsum=1/csum
    }
    __syncthreads();
    float inv = bc[0], icsum = bc[1];
#pragma unroll
    for (int k = 0; k < 8; ++k)
        W[((size_t)gb * 75 + t) * 2048 + tid + 256 * k] = ent[k] * inv;
#pragma unroll
    for (int k = 0; k < 8; ++k) red8[k][tid] = __expf(pe[k] * icsum);
    __syncthreads();
    if (tid < 128) {
#pragma unroll
        for (int k = 0; k < 8; ++k) red8[k][tid] += red8[k][tid + 128];
    }
    __syncthreads();
    if (tid < 64) {
        float v[8];
#pragma unroll
        for (int k = 0; k < 8; ++k) v[k] = red8[k][tid] + red8[k][tid + 64];
#pragma unroll
        for (int k = 0; k < 8; ++k) { SHFL_TAIL_ADD(v[k]) }
        if (tid == 0) {
#pragma unroll
            for (int k = 0; k < 8; ++k)
                SD[((size_t)gb * 8 + k) * 75 + t] = v[k];
        }
    }
}

// K4: v_tidal partials per m-cell. Round-5 PROVEN core: XOR-swizzled V +
// WtT LDS staging. NEW: th==0 blocks also accumulate vns[d] = sum_hw
// v[hw][d]*rn[hw] from the SAME vv registers the PV loop already loads
// (rn[hw] is a lane-uniform LDS broadcast; +4 FMA/step), and write it to the
// VNS slot — k5k6's k6 path then skips its entire 80MB image re-read.
// rn bits identical to old k6 (same staged nsq); vns sum order is now
// hw-sequential (was tree) -> final scalar may differ by ~1 ulp (accepted).
__global__ __launch_bounds__(256, 2) void k4_vtidal(const float* __restrict__ image,
                                                    float* __restrict__ ws) {
    __shared__ __align__(16) float V[32 * 256];  // [rr][swizzled d-block]
    __shared__ __align__(16) float WtT[32][52];  // [rr][w*12 + j]
    __shared__ float rnps[256];                  // rn[hw] (th==0) / zeros (th==1)
    const float* W = ws + OFF_W;
    float* VTP = ws + OFF_S; // s is dead; reuse
    int blk = blockIdx.x;
    int th = blk >= 320 ? 1 : 0;
    int rest = blk - th * 320;
    int m = rest & 7, gb = rest >> 3;
    int tb = th * 40;
    const float* cell = image + (size_t)(gb * 8 + m) * ND * NHW; // [d][hw]
    int tid = threadIdx.x;
    int lane = tid & 63;
    int w = __builtin_amdgcn_readfirstlane(tid >> 6); // 0..3; wave owns t = tb+w*10+j
    int d4 = lane * 4;
    int rr4  = (tid & 7) * 4;     // V rr base for this thread's float4
    int drow = tid >> 3;          // d = drow + 32*i
    int wrr  = tid & 31;          // WtT rr
    int wtc0 = tid >> 5;          // tcl = wtc0 + 8*i
    bool dovns = (th == 0);
    {
        float nsq = 0.f;
        if (dovns) nsq = ws[OFF_VNS + (size_t)(gb * 8 + m) * 256 + tid];
        rnps[tid] = dovns ? 1.f / fmaxf(sqrtf(nsq), 1e-12f) : 0.f;
    }
    float4 acc[10];
#pragma unroll
    for (int j = 0; j < 10; ++j) acc[j] = make_float4(0.f, 0.f, 0.f, 0.f);
    float4 vnsacc = make_float4(0.f, 0.f, 0.f, 0.f);
    const float* wb = W + (size_t)gb * 75 * 2048 + m * 256;
    float4 p0, p1, p2, p3, p4, p5, p6, p7;
    float w0, w1, w2, w3, w4;
#define K4_T(I) ((tb + wtc0 + 8 * (I)) > 74 ? 74 : (tb + wtc0 + 8 * (I)))
#define K4_LOAD(RC)                                                               \
    p0 = *(const float4*)&cell[(size_t)(drow +   0) * 256 + (RC) * 32 + rr4];     \
    p1 = *(const float4*)&cell[(size_t)(drow +  32) * 256 + (RC) * 32 + rr4];     \
    p2 = *(const float4*)&cell[(size_t)(drow +  64) * 256 + (RC) * 32 + rr4];     \
    p3 = *(const float4*)&cell[(size_t)(drow +  96) * 256 + (RC) * 32 + rr4];     \
    p4 = *(const float4*)&cell[(size_t)(drow + 128) * 256 + (RC) * 32 + rr4];     \
    p5 = *(const float4*)&cell[(size_t)(drow + 160) * 256 + (RC) * 32 + rr4];     \
    p6 = *(const float4*)&cell[(size_t)(drow + 192) * 256 + (RC) * 32 + rr4];     \
    p7 = *(const float4*)&cell[(size_t)(drow + 224) * 256 + (RC) * 32 + rr4];     \
    w0 = wb[(size_t)K4_T(0) * 2048 + (RC) * 32 + wrr];                            \
    w1 = wb[(size_t)K4_T(1) * 2048 + (RC) * 32 + wrr];                            \
    w2 = wb[(size_t)K4_T(2) * 2048 + (RC) * 32 + wrr];                            \
    w3 = wb[(size_t)K4_T(3) * 2048 + (RC) * 32 + wrr];                            \
    w4 = wb[(size_t)K4_T(4) * 2048 + (RC) * 32 + wrr];
#define K4_WCOL(I) (((wtc0 + 8 * (I)) / 10) * 12 + ((wtc0 + 8 * (I)) % 10))
// swizzled V address for (row RR, column D): block (D>>2) ^ ((RR>>2)&7)
#define K4_VADDR(RR, D) (((RR) << 8) + ((((D) >> 2) ^ (((RR) >> 2) & 7)) << 2) + ((D) & 3))
#define K4_VST(P, DOFF)                                                           \
    V[K4_VADDR(rr4 + 0, drow + (DOFF))] = (P).x;                                  \
    V[K4_VADDR(rr4 + 1, drow + (DOFF))] = (P).y;                                  \
    V[K4_VADDR(rr4 + 2, drow + (DOFF))] = (P).z;                                  \
    V[K4_VADDR(rr4 + 3, drow + (DOFF))] = (P).w;
    K4_LOAD(0)
    for (int rc = 0; rc < 8; ++rc) {
        __syncthreads();
        K4_VST(p0,   0) K4_VST(p1,  32) K4_VST(p2,  64) K4_VST(p3,  96)
        K4_VST(p4, 128) K4_VST(p5, 160) K4_VST(p6, 192) K4_VST(p7, 224)
        WtT[wrr][K4_WCOL(0)] = w0;
        WtT[wrr][K4_WCOL(1)] = w1;
        WtT[wrr][K4_WCOL(2)] = w2;
        WtT[wrr][K4_WCOL(3)] = w3;
        WtT[wrr][K4_WCOL(4)] = w4;
        __syncthreads();
        if (rc < 7) { K4_LOAD(rc + 1) }
        for (int rr = 0; rr < 32; ++rr) {
            int sr = (rr >> 2) & 7;
            float4 vv = *(const float4*)&V[(rr << 8) + ((lane ^ sr) << 2)];
            float rv = rnps[(rc << 5) + rr];   // lane-uniform broadcast
            vnsacc.x += vv.x * rv; vnsacc.y += vv.y * rv;
            vnsacc.z += vv.z * rv; vnsacc.w += vv.w * rv;
            float4 q0 = *(const float4*)&WtT[rr][w * 12];
            float4 q1 = *(const float4*)&WtT[rr][w * 12 + 4];
            float2 q2 = *(const float2*)&WtT[rr][w * 12 + 8];
            float wv[10] = {q0.x, q0.y, q0.z, q0.w, q1.x, q1.y, q1.z, q1.w, q2.x, q2.y};
#pragma unroll
            for (int j = 0; j < 10; ++j) {
                acc[j].x += vv.x * wv[j]; acc[j].y += vv.y * wv[j];
                acc[j].z += vv.z * wv[j]; acc[j].w += vv.w * wv[j];
            }
        }
    }
#undef K4_LOAD
#undef K4_T
#undef K4_WCOL
#undef K4_VADDR
#undef K4_VST
#pragma unroll
    for (int j = 0; j < 10; ++j) {
        int t = tb + w * 10 + j;
        if (t < 75)
            *(float4*)&VTP[((size_t)(gb * 8 + m) * 75 + t) * 256 + d4] = acc[j];
    }
    if (dovns && w == 0)
        *(float4*)&ws[OFF_VNS + (size_t)(gb * 8 + m) * 256 + d4] = vnsacc;
}

// K5+K6 MERGED LAUNCH: blocks 0..319 = k6/k7 path — now WITHOUT the vns
// image pass (k4 supplies vns via the VNS slot): just beta/em/logit2.
// Blocks 320..3319 = k5 logit path. LDS union shrinks 38.7KB -> 3KB,
// un-capping occupancy from 4 to 8 blocks/CU for the whole merged kernel.
__global__ __launch_bounds__(256) void k5k6(const float* __restrict__ image,
                                            const float* __restrict__ text,
                                            float* __restrict__ ws) {
    __shared__ __align__(16) float smem[768];
    __shared__ float sdv[80];
    __shared__ float segs[8];
    __shared__ float betas[80];
    int blk = blockIdx.x;
    int tid = threadIdx.x;
    if (blk < 320) {
        // ---- k6/k7 path (beta + em + logit2; vns precomputed by k4) ----
        float* rA = smem;
        float* rB = smem + 256;
        const float* SD = ws + OFF_SD;
        float* BETA = ws + OFF_BETA;
        float* LG2 = ws + OFF_LG2;
        int m = blk & 7, gb = blk >> 3, g = gb / 5;
        float vns = ws[OFF_VNS + (size_t)(gb * 8 + m) * 256 + tid];  // from k4
        if (tid < 75) sdv[tid] = SD[((size_t)gb * 8 + m) * 75 + tid];
        __syncthreads();
        if (tid < 5) {
            float s = 0.f;
            for (int l = 0; l < 15; ++l) s += sdv[tid * 15 + l];
            segs[tid] = s;
        }
        __syncthreads();
        if (tid < 75) {
            float b = sdv[tid] / segs[tid / 15];
            betas[tid] = b;
            BETA[((size_t)gb * 8 + m) * 75 + tid] = b;
        }
        __syncthreads();
        for (int s = 0; s < 5; ++s) {
            float em = 0.f;
#pragma unroll
            for (int l = 0; l < 15; ++l)
                em += betas[s * 15 + l] * text[((size_t)(g * 5 + s) * 15 + l) * 256 + tid];
            rA[tid] = em * em; rB[tid] = em * vns;
            __syncthreads();
            if (tid < 128) { rA[tid] += rA[tid + 128]; rB[tid] += rB[tid + 128]; }
            __syncthreads();
            if (tid < 64) {
                float a = rA[tid] + rA[tid + 64];
                float b = rB[tid] + rB[tid + 64];
                SHFL_TAIL_ADD(a)
                SHFL_TAIL_ADD(b)
                if (tid == 0)
                    LG2[((size_t)gb * 8 + m) * 5 + s] =
                        b / fmaxf(sqrtf(a), 1e-12f) * (1.f / 256.f);
            }
            __syncthreads();  // rA/rB reused next segment
        }
    } else {
        // ---- k5 logit path ----
        float* rA = smem;          // 256
        float* rB = smem + 256;    // 256
        float* rC = smem + 512;    // 256
        const float* VTP = ws + OFF_S;
        float* LG = ws + OFF_LG;
        int b2 = blk - 320;
        int t = b2 % 75, gb = b2 / 75, g = gb / 5;
        float vt = 0.f;
#pragma unroll
        for (int m = 0; m < 8; ++m)
            vt += VTP[((size_t)(gb * 8 + m) * 75 + t) * 256 + tid];
        int seg = t / 15, l = t % 15;
        float ev = text[((size_t)(g * 5 + seg) * 15 + l) * 256 + tid];
        rA[tid] = vt * vt; rB[tid] = ev * ev; rC[tid] = vt * ev;
        __syncthreads();
        if (tid < 128) {
            rA[tid] += rA[tid + 128];
            rB[tid] += rB[tid + 128];
            rC[tid] += rC[tid + 128];
        }
        __syncthreads();
        if (tid < 64) {
            float a = rA[tid] + rA[tid + 64];
            float b = rB[tid] + rB[tid + 64];
            float c = rC[tid] + rC[tid + 64];
            SHFL_TAIL_ADD(a)
            SHFL_TAIL_ADD(b)
            SHFL_TAIL_ADD(c)
            if (tid == 0)
                LG[gb * 75 + t] = c / (fmaxf(sqrtf(a), 1e-12f) * fmaxf(sqrtf(b), 1e-12f));
        }
    }
}

// K8: per-g block assembly -> BLK[g]  (8 blocks — round-10 showed the
// single-block merge serializes the offsq work onto one CU, ~15us loss)
__global__ __launch_bounds__(256) void k8_final(float* __restrict__ ws) {
    __shared__ float lsm[5][5];
    __shared__ float offsq[5][64];
    __shared__ float regs[5];
    const float* LG = ws + OFF_LG;
    const float* LG2 = ws + OFF_LG2;
    const float* BETA = ws + OFF_BETA;
    float* BLK = ws + OFF_BLK;
    int g = blockIdx.x;
    int tid = threadIdx.x;
    if (tid < 25) {
        int b = tid / 5, s = tid % 5;
        int gb = g * 5 + b;
        float s1 = 0.f;
        for (int l = 0; l < 15; ++l) s1 += expf(LG[gb * 75 + s * 15 + l]);
        float s2 = 0.f;
        for (int mm = 0; mm < 8; ++mm) s2 += expf(LG2[((size_t)gb * 8 + mm) * 5 + s]);
        float l1 = logf(powf(s1, 0.2f) + 1e-10f);
        float l2 = logf(powf(s2, 0.2f) + 1e-10f);
        lsm[b][s] = 10.f * (l1 + l2);
    }
    for (int p = tid; p < 320; p += 256) {
        int b = p >> 6, mn = p & 63, mm = mn >> 3, nn = mn & 7;
        int gb = g * 5 + b;
        const float* bm = BETA + ((size_t)gb * 8 + mm) * 75;
        const float* bn = BETA + ((size_t)gb * 8 + nn) * 75;
        float acc = 0.f;
        for (int t2 = 0; t2 < 75; ++t2) acc += bm[t2] * bn[t2];
        offsq[b][mn] = (mm == nn) ? 0.f : acc * acc;
    }
    __syncthreads();
    if (tid < 5) {
        float s = 0.f;
        for (int i = 0; i < 64; ++i) s += offsq[tid][i];
        regs[tid] = sqrtf(s);
    }
    __syncthreads();
    if (tid == 0) {
        float loss_reg = 0.f;
        for (int b = 0; b < 5; ++b) loss_reg += regs[b];
        loss_reg *= 0.2f;
        float pdq = 0.f, pqd = 0.f;
        for (int i = 0; i < 5; ++i) {
            float rsum = 0.f, csum = 0.f;
            for (int j = 0; j < 5; ++j) { rsum += lsm[i][j]; csum += lsm[j][i]; }
            float di = lsm[i][i];
            pdq += -logf(di / rsum + 1e-10f);
            pqd += -logf(di / csum + 1e-10f);
        }
        BLK[g] = (pdq + pqd) * 0.2f + loss_reg;
    }
}

__global__ void k9_out(const float* __restrict__ ws, float* __restrict__ out) {
    if (threadIdx.x == 0) {
        float s = 0.f;
        for (int g2 = 0; g2 < 8; ++g2) s += ws[OFF_BLK + g2];
        out[0] = s / 9.f;
    }
}

extern "C" void kernel_launch(void* const* d_in, const int* in_sizes, int n_in,
                              void* d_out, int out_size, void* d_ws, size_t ws_size,
                              hipStream_t stream) {
    const float* image = (const float*)d_in[0];
    const float* text  = (const float*)d_in[1];
    float* ws = (float*)d_ws;
    float* out = (float*)d_out;
    hipLaunchKernelGGL(k1_gemm_s,   dim3(640),  dim3(256), 0, stream, image, text, ws);
    hipLaunchKernelGGL(k2_rowstats, dim3(1600), dim3(256), 0, stream, ws);
    hipLaunchKernelGGL(k3_colstats, dim3(3000), dim3(256), 0, stream, ws);
    hipLaunchKernelGGL(k4_vtidal,   dim3(640),  dim3(256), 0, stream, image, ws);
    hipLaunchKernelGGL(k5k6,        dim3(3320), dim3(256), 0, stream, image, text, ws);
    hipLaunchKernelGGL(k8_final,    dim3(8),    dim3(256), 0, stream, ws);
    hipLaunchKernelGGL(k9_out,      dim3(1),    dim3(64),  0, stream, ws, out);
}